// Round 1
// baseline (174.778 us; speedup 1.0000x reference)
//
#include <hip/hip_runtime.h>

// Problem constants (baked in; reference: B=32, C=3, H=W=512, bs=8, nf=4,
// input_dim=16384, output_dim=512)
#define K_DIM   16384
#define N_OUT   512
#define N_BATCH 32

// ---------------------------------------------------------------------------
// Kernel 1: feats. Only dct row k=0, cols m=0..3 survive -> column sums of
// each 8x8 block combined with cos(pi*m*l/4)/8.
// feats[b, ((i*64+j)*4 + m)] ; one thread per (b,i,j) block.
// ---------------------------------------------------------------------------
__global__ __launch_bounds__(256) void feats_kernel(
    const float* __restrict__ imgs, float* __restrict__ feats) {
    int t = blockIdx.x * 256 + threadIdx.x;   // 0..131071
    int b  = t >> 12;                         // /4096
    int ij = t & 4095;
    int i  = ij >> 6;
    int j  = ij & 63;

    const float* x = imgs + (size_t)b * (3 * 512 * 512);  // channel 0
    int base = (i * 8) * 512 + j * 8;

    float4 cs0 = make_float4(0.f, 0.f, 0.f, 0.f);  // colsums l=0..3
    float4 cs1 = make_float4(0.f, 0.f, 0.f, 0.f);  // colsums l=4..7
#pragma unroll
    for (int r = 0; r < 8; ++r) {
        const float4* p = (const float4*)(x + base + r * 512);
        float4 a = p[0];
        float4 c = p[1];
        cs0.x += a.x; cs0.y += a.y; cs0.z += a.z; cs0.w += a.w;
        cs1.x += c.x; cs1.y += c.y; cs1.z += c.z; cs1.w += c.w;
    }
    const float S = 0.70710678118654752440f;  // sqrt(2)/2
    float t1 = cs0.y - cs0.w - cs1.y + cs1.w; // cs1-cs3-cs5+cs7
    float4 f;
    f.x = 0.125f * (cs0.x + cs0.y + cs0.z + cs0.w + cs1.x + cs1.y + cs1.z + cs1.w);
    f.y = 0.125f * (cs0.x - cs1.x + S * t1);
    f.z = 0.125f * (cs0.x - cs0.z + cs1.x - cs1.z);
    f.w = 0.125f * (cs0.x - cs1.x - S * t1);
    ((float4*)feats)[t] = f;
}

// ---------------------------------------------------------------------------
// Kernel 2: out[b,o] = bias[o]  (out is poisoned before every launch)
// ---------------------------------------------------------------------------
__global__ __launch_bounds__(256) void bias_init_kernel(
    const float* __restrict__ bias, float* __restrict__ out) {
    int t = blockIdx.x * 256 + threadIdx.x;   // 0..16383
    out[t] = bias[t & (N_OUT - 1)];
}

// ---------------------------------------------------------------------------
// Kernel 3: split-K GEMM, out[b,o] += sum_k feats[b,k]*W[o,k]
// grid (64 row-groups, 8 k-splits); block 256 = 4 waves.
// wave w: rows r0..r0+7 x batches w*8..w*8+7, lanes over k (float4).
// Epilogue: LDS transpose (+1 pad -> stride 65, conflict-free) then atomicAdd.
// ---------------------------------------------------------------------------
#define NR     8      // rows per block
#define NBW    8      // batches per wave
#define KSPLIT 8
#define KC     (K_DIM / KSPLIT)   // 2048 k per block

__global__ __launch_bounds__(256, 2) void gemm_kernel(
    const float* __restrict__ W, const float* __restrict__ feats,
    float* __restrict__ out) {
    const int rg  = blockIdx.x;          // 0..63
    const int kc  = blockIdx.y;          // 0..7
    const int tid = threadIdx.x;
    const int wv_id = tid >> 6;          // wave -> batch group
    const int l     = tid & 63;
    const int r0 = rg * NR;
    const int b0 = wv_id * NBW;

    const float4* W4 = (const float4*)W;
    const float4* F4 = (const float4*)feats;
    const int k4base = kc * (KC / 4) + l;   // float4 index within a row

    float acc[NR][NBW];
#pragma unroll
    for (int r = 0; r < NR; ++r)
#pragma unroll
        for (int b = 0; b < NBW; ++b) acc[r][b] = 0.f;

#pragma unroll 2
    for (int ki = 0; ki < KC / 256; ++ki) {   // 8 iterations
        const int k4 = k4base + ki * 64;
        float4 wreg[NR];
        float4 freg[NBW];
#pragma unroll
        for (int r = 0; r < NR; ++r)
            wreg[r] = W4[(size_t)(r0 + r) * (K_DIM / 4) + k4];
#pragma unroll
        for (int b = 0; b < NBW; ++b)
            freg[b] = F4[(size_t)(b0 + b) * (K_DIM / 4) + k4];
#pragma unroll
        for (int r = 0; r < NR; ++r)
#pragma unroll
            for (int b = 0; b < NBW; ++b) {
                acc[r][b] += wreg[r].x * freg[b].x + wreg[r].y * freg[b].y +
                             wreg[r].z * freg[b].z + wreg[r].w * freg[b].w;
            }
    }

    // --- cross-lane reduction via padded LDS transpose ---
    __shared__ float red[4][NR][NBW][65];   // 65: +1 pad, 66.5 KB total
#pragma unroll
    for (int r = 0; r < NR; ++r)
#pragma unroll
        for (int b = 0; b < NBW; ++b)
            red[wv_id][r][b][l] = acc[r][b];
    __syncthreads();

    // each thread owns one (row r, batch b) output partial
    const int r  = tid >> 5;        // 0..7
    const int b  = tid & 31;        // 0..31  (global batch)
    const int wsrc = b >> 3;
    const int bb   = b & 7;
    float sum = 0.f;
#pragma unroll
    for (int i = 0; i < 64; ++i) sum += red[wsrc][r][bb][i];
    atomicAdd(&out[(size_t)b * N_OUT + (r0 + r)], sum);
}

// ---------------------------------------------------------------------------
extern "C" void kernel_launch(void* const* d_in, const int* in_sizes, int n_in,
                              void* d_out, int out_size, void* d_ws, size_t ws_size,
                              hipStream_t stream) {
    const float* imgs   = (const float*)d_in[0];  // (32,3,512,512) f32
    const float* weight = (const float*)d_in[1];  // (512,16384) f32
    const float* bias   = (const float*)d_in[2];  // (512,) f32
    // d_in[3]=block_size, d_in[4]=num_features -> constants baked in
    float* out   = (float*)d_out;                 // (32,512) f32
    float* feats = (float*)d_ws;                  // 32*16384 f32 = 2 MB scratch

    feats_kernel<<<512, 256, 0, stream>>>(imgs, feats);
    bias_init_kernel<<<N_BATCH * N_OUT / 256, 256, 0, stream>>>(bias, out);
    gemm_kernel<<<dim3(N_OUT / NR, KSPLIT), 256, 0, stream>>>(weight, feats, out);
}

// Round 2
// 173.585 us; speedup vs baseline: 1.0069x; 1.0069x over previous
//
#include <hip/hip_runtime.h>

// Problem constants (reference: B=32, C=3, H=W=512, bs=8, nf=4,
// input_dim=16384, output_dim=512)
#define K_DIM   16384
#define N_OUT   512
#define N_BATCH 32

// ---------------------------------------------------------------------------
// Kernel 1: feats. Only dct row k=0, cols m=0..3 survive -> column sums of
// each 8x8 block combined with cos(pi*m*l/4)/8.
// feats[b, ((i*64+j)*4 + m)] ; one thread per (b,i,j) block.
// ---------------------------------------------------------------------------
__global__ __launch_bounds__(256) void feats_kernel(
    const float* __restrict__ imgs, float* __restrict__ feats) {
    int t = blockIdx.x * 256 + threadIdx.x;   // 0..131071
    int b  = t >> 12;                         // /4096
    int ij = t & 4095;
    int i  = ij >> 6;
    int j  = ij & 63;

    const float* x = imgs + (size_t)b * (3 * 512 * 512);  // channel 0
    int base = (i * 8) * 512 + j * 8;

    float4 cs0 = make_float4(0.f, 0.f, 0.f, 0.f);  // colsums l=0..3
    float4 cs1 = make_float4(0.f, 0.f, 0.f, 0.f);  // colsums l=4..7
#pragma unroll
    for (int r = 0; r < 8; ++r) {
        const float4* p = (const float4*)(x + base + r * 512);
        float4 a = p[0];
        float4 c = p[1];
        cs0.x += a.x; cs0.y += a.y; cs0.z += a.z; cs0.w += a.w;
        cs1.x += c.x; cs1.y += c.y; cs1.z += c.z; cs1.w += c.w;
    }
    const float S = 0.70710678118654752440f;  // sqrt(2)/2
    float t1 = cs0.y - cs0.w - cs1.y + cs1.w;
    float4 f;
    f.x = 0.125f * (cs0.x + cs0.y + cs0.z + cs0.w + cs1.x + cs1.y + cs1.z + cs1.w);
    f.y = 0.125f * (cs0.x - cs1.x + S * t1);
    f.z = 0.125f * (cs0.x - cs0.z + cs1.x - cs1.z);
    f.w = 0.125f * (cs0.x - cs1.x - S * t1);
    ((float4*)feats)[t] = f;
}

// ---------------------------------------------------------------------------
// Kernel 2: out[b,o] = bias[o]  (out is poisoned before every launch)
// ---------------------------------------------------------------------------
__global__ __launch_bounds__(256) void bias_init_kernel(
    const float* __restrict__ bias, float* __restrict__ out) {
    int t = blockIdx.x * 256 + threadIdx.x;   // 0..16383
    out[t] = bias[t & (N_OUT - 1)];
}

// ---------------------------------------------------------------------------
// Kernel 3: split-K GEMM, out[b,o] += sum_k feats[b,k]*W[o,k]
// grid (64 row-groups, 8 k-splits); block = 512 threads = 8 waves.
// Block tile: 8 rows x 32 batches x KC=2048 k.
// Wave wv: rows (wv&1)*4..+4, batches (wv>>1)*8..+8 -> acc[4][8] = 32 VGPR,
// 12 float4 loads in flight (48 VGPR). ~95 VGPR total -> no spill at the
// __launch_bounds__(512,4) cap of 128, 4 waves/SIMD, 2 blocks/CU.
// Epilogue: padded-LDS transpose (stride 65) -> 64-term sums -> atomicAdd.
// ---------------------------------------------------------------------------
#define NRW    4      // rows per wave
#define NBW    8      // batches per wave
#define KSPLIT 8
#define KC     (K_DIM / KSPLIT)   // 2048 k per block

__global__ __launch_bounds__(512, 4) void gemm_kernel(
    const float* __restrict__ W, const float* __restrict__ feats,
    float* __restrict__ out) {
    const int rg  = blockIdx.x;          // 0..63
    const int kc  = blockIdx.y;          // 0..7
    const int tid = threadIdx.x;
    const int wv  = tid >> 6;            // 0..7
    const int l   = tid & 63;
    const int r0    = rg * 8;
    const int rsub  = (wv & 1) * NRW;    // row half
    const int bgrp  = (wv >> 1) * NBW;   // batch group

    const float4* W4 = (const float4*)W;
    const float4* F4 = (const float4*)feats;
    const int k4base = kc * (KC / 4) + l;

    float acc[NRW][NBW];
#pragma unroll
    for (int r = 0; r < NRW; ++r)
#pragma unroll
        for (int b = 0; b < NBW; ++b) acc[r][b] = 0.f;

    for (int ki = 0; ki < KC / 256; ++ki) {   // 8 iterations
        const int k4 = k4base + ki * 64;
        float4 wreg[NRW];
        float4 freg[NBW];
#pragma unroll
        for (int r = 0; r < NRW; ++r)
            wreg[r] = W4[(size_t)(r0 + rsub + r) * (K_DIM / 4) + k4];
#pragma unroll
        for (int b = 0; b < NBW; ++b)
            freg[b] = F4[(size_t)(bgrp + b) * (K_DIM / 4) + k4];
#pragma unroll
        for (int r = 0; r < NRW; ++r)
#pragma unroll
            for (int b = 0; b < NBW; ++b) {
                acc[r][b] += wreg[r].x * freg[b].x + wreg[r].y * freg[b].y +
                             wreg[r].z * freg[b].z + wreg[r].w * freg[b].w;
            }
    }

    // --- cross-lane reduction via padded LDS transpose (66.5 KB) ---
    __shared__ float red[8][NRW][NBW][65];
#pragma unroll
    for (int r = 0; r < NRW; ++r)
#pragma unroll
        for (int b = 0; b < NBW; ++b)
            red[wv][r][b][l] = acc[r][b];
    __syncthreads();

    if (tid < 256) {
        const int orow = tid >> 5;       // 0..7 row within block
        const int b    = tid & 31;       // global batch
        const int wsrc = (b >> 3) * 2 + (orow >> 2);
        const int rsrc = orow & 3;
        const int bsrc = b & 7;
        float sum = 0.f;
#pragma unroll
        for (int i = 0; i < 64; ++i) sum += red[wsrc][rsrc][bsrc][i];
        atomicAdd(&out[(size_t)b * N_OUT + (r0 + orow)], sum);
    }
}

// ---------------------------------------------------------------------------
extern "C" void kernel_launch(void* const* d_in, const int* in_sizes, int n_in,
                              void* d_out, int out_size, void* d_ws, size_t ws_size,
                              hipStream_t stream) {
    const float* imgs   = (const float*)d_in[0];  // (32,3,512,512) f32
    const float* weight = (const float*)d_in[1];  // (512,16384) f32
    const float* bias   = (const float*)d_in[2];  // (512,) f32
    float* out   = (float*)d_out;                 // (32,512) f32
    float* feats = (float*)d_ws;                  // 32*16384 f32 = 2 MB scratch

    feats_kernel<<<512, 256, 0, stream>>>(imgs, feats);
    bias_init_kernel<<<N_BATCH * N_OUT / 256, 256, 0, stream>>>(bias, out);
    gemm_kernel<<<dim3(N_OUT / 8, KSPLIT), 512, 0, stream>>>(weight, feats, out);
}

// Round 3
// 172.029 us; speedup vs baseline: 1.0160x; 1.0090x over previous
//
#include <hip/hip_runtime.h>

// Problem constants (reference: B=32, C=3, H=W=512, bs=8, nf=4,
// input_dim=16384, output_dim=512)
#define K_DIM   16384
#define N_OUT   512
#define N_BATCH 32

// ---------------------------------------------------------------------------
// Kernel 1: feats + bias-init fused.
// Only dct row k=0, cols m=0..3 survive -> column sums of each 8x8 block
// combined with cos(pi*m*l/4)/8.  feats[b, ((i*64+j)*4 + m)].
// One thread per (b,i,j) block; threads t<16384 also write out[t]=bias[t&511]
// (out is re-poisoned to 0xAA before every launch, so it must be initialized
// here before gemm's atomicAdds).
// ---------------------------------------------------------------------------
__global__ __launch_bounds__(256) void feats_bias_kernel(
    const float* __restrict__ imgs, const float* __restrict__ bias,
    float* __restrict__ feats, float* __restrict__ out) {
    int t = blockIdx.x * 256 + threadIdx.x;   // 0..131071

    if (t < N_BATCH * N_OUT)                  // first 64 blocks
        out[t] = bias[t & (N_OUT - 1)];

    int b  = t >> 12;                         // /4096
    int ij = t & 4095;
    int i  = ij >> 6;
    int j  = ij & 63;

    const float* x = imgs + (size_t)b * (3 * 512 * 512);  // channel 0
    int base = (i * 8) * 512 + j * 8;

    float4 cs0 = make_float4(0.f, 0.f, 0.f, 0.f);  // colsums l=0..3
    float4 cs1 = make_float4(0.f, 0.f, 0.f, 0.f);  // colsums l=4..7
#pragma unroll
    for (int r = 0; r < 8; ++r) {
        const float4* p = (const float4*)(x + base + r * 512);
        float4 a = p[0];
        float4 c = p[1];
        cs0.x += a.x; cs0.y += a.y; cs0.z += a.z; cs0.w += a.w;
        cs1.x += c.x; cs1.y += c.y; cs1.z += c.z; cs1.w += c.w;
    }
    const float S = 0.70710678118654752440f;  // sqrt(2)/2
    float t1 = cs0.y - cs0.w - cs1.y + cs1.w;
    float4 f;
    f.x = 0.125f * (cs0.x + cs0.y + cs0.z + cs0.w + cs1.x + cs1.y + cs1.z + cs1.w);
    f.y = 0.125f * (cs0.x - cs1.x + S * t1);
    f.z = 0.125f * (cs0.x - cs0.z + cs1.x - cs1.z);
    f.w = 0.125f * (cs0.x - cs1.x - S * t1);
    ((float4*)feats)[t] = f;
}

// ---------------------------------------------------------------------------
// Kernel 2: split-K GEMM, out[b,o] += sum_k feats[b,k]*W[o,k]
// grid (64 row-groups, 8 k-splits); block = 512 threads = 8 waves.
// Block tile: 8 rows x 32 batches x KC=2048 k.
// Wave wv: rows (wv&1)*4..+4, batches (wv>>1)*8..+8 -> acc[4][8] = 32 VGPR,
// 12 float4 loads in flight. ~95 VGPR -> no spill under the
// __launch_bounds__(512,4) cap of 128; 4 waves/SIMD, 2 blocks/CU.
// Epilogue: padded-LDS transpose (stride 65) -> 64-term sums -> atomicAdd.
// ---------------------------------------------------------------------------
#define NRW    4      // rows per wave
#define NBW    8      // batches per wave
#define KSPLIT 8
#define KC     (K_DIM / KSPLIT)   // 2048 k per block

__global__ __launch_bounds__(512, 4) void gemm_kernel(
    const float* __restrict__ W, const float* __restrict__ feats,
    float* __restrict__ out) {
    const int rg  = blockIdx.x;          // 0..63
    const int kc  = blockIdx.y;          // 0..7
    const int tid = threadIdx.x;
    const int wv  = tid >> 6;            // 0..7
    const int l   = tid & 63;
    const int r0    = rg * 8;
    const int rsub  = (wv & 1) * NRW;    // row half
    const int bgrp  = (wv >> 1) * NBW;   // batch group

    const float4* W4 = (const float4*)W;
    const float4* F4 = (const float4*)feats;
    const int k4base = kc * (KC / 4) + l;

    float acc[NRW][NBW];
#pragma unroll
    for (int r = 0; r < NRW; ++r)
#pragma unroll
        for (int b = 0; b < NBW; ++b) acc[r][b] = 0.f;

    for (int ki = 0; ki < KC / 256; ++ki) {   // 8 iterations
        const int k4 = k4base + ki * 64;
        float4 wreg[NRW];
        float4 freg[NBW];
#pragma unroll
        for (int r = 0; r < NRW; ++r)
            wreg[r] = W4[(size_t)(r0 + rsub + r) * (K_DIM / 4) + k4];
#pragma unroll
        for (int b = 0; b < NBW; ++b)
            freg[b] = F4[(size_t)(bgrp + b) * (K_DIM / 4) + k4];
#pragma unroll
        for (int r = 0; r < NRW; ++r)
#pragma unroll
            for (int b = 0; b < NBW; ++b) {
                acc[r][b] += wreg[r].x * freg[b].x + wreg[r].y * freg[b].y +
                             wreg[r].z * freg[b].z + wreg[r].w * freg[b].w;
            }
    }

    // --- cross-lane reduction via padded LDS transpose (66.5 KB) ---
    __shared__ float red[8][NRW][NBW][65];
#pragma unroll
    for (int r = 0; r < NRW; ++r)
#pragma unroll
        for (int b = 0; b < NBW; ++b)
            red[wv][r][b][l] = acc[r][b];
    __syncthreads();

    if (tid < 256) {
        const int orow = tid >> 5;       // 0..7 row within block
        const int b    = tid & 31;       // global batch
        const int wsrc = (b >> 3) * 2 + (orow >> 2);
        const int rsrc = orow & 3;
        const int bsrc = b & 7;
        float sum = 0.f;
#pragma unroll
        for (int i = 0; i < 64; ++i) sum += red[wsrc][rsrc][bsrc][i];
        atomicAdd(&out[(size_t)b * N_OUT + (r0 + orow)], sum);
    }
}

// ---------------------------------------------------------------------------
extern "C" void kernel_launch(void* const* d_in, const int* in_sizes, int n_in,
                              void* d_out, int out_size, void* d_ws, size_t ws_size,
                              hipStream_t stream) {
    const float* imgs   = (const float*)d_in[0];  // (32,3,512,512) f32
    const float* weight = (const float*)d_in[1];  // (512,16384) f32
    const float* bias   = (const float*)d_in[2];  // (512,) f32
    float* out   = (float*)d_out;                 // (32,512) f32
    float* feats = (float*)d_ws;                  // 32*16384 f32 = 2 MB scratch

    feats_bias_kernel<<<512, 256, 0, stream>>>(imgs, bias, feats, out);
    gemm_kernel<<<dim3(N_OUT / 8, KSPLIT), 512, 0, stream>>>(weight, feats, out);
}